// Round 1
// baseline (94.629 us; speedup 1.0000x reference)
//
#include <hip/hip_runtime.h>
#include <math.h>

#define BQ 256   // batch
#define NXQ 256  // spatial points
#define TQ 100   // time steps
#define N2 512   // 2*B
#define TILE 32
#define PITCH 257  // 257 % 32 == 1 -> conflict-free row access

// ---------------------------------------------------------------------------
// K1: build A[r][x] = u[r%B,x,T-1] + rep[r,x]
//           C[r][x] = u[r%B,x,T-2] + rep[r,x] + upd(rep, dt, vs, dx)[x]
//     and SS[i][j] = nan_to_num(1 - 0.9*sim(vs_i, vs_j))
// ---------------------------------------------------------------------------
__global__ __launch_bounds__(256) void prep_kernel(
    const float* __restrict__ x1, const float* __restrict__ x2,
    const float* __restrict__ u, const float* __restrict__ dt,
    const float* __restrict__ dx, const float* __restrict__ vs,
    float* __restrict__ A, float* __restrict__ C, float* __restrict__ SS) {
  int blk = blockIdx.x;
  int t = threadIdx.x;
  if (blk < N2) {
    int r = blk;
    int b = r & (BQ - 1);
    const float* xr = (r < BQ ? x2 : x1);  // reps = concat([x2, x1])
    __shared__ float ws[NXQ];
    ws[t] = xr[b * NXQ + t];
    __syncthreads();
    float w0 = ws[t];
    float wm = ws[(t + NXQ - 1) & (NXQ - 1)];  // roll(+1): u[x-1]
    float wp = ws[(t + 1) & (NXQ - 1)];        // roll(-1): u[x+1]
    float dtv = dt[b];
    float dxv = dx[0];
    float c0 = vs[b * 3 + 0], c1 = vs[b * 3 + 1], c2 = vs[b * 3 + 2];
    float adv = c0 * dtv * (wm - wp) * w0 / (2.0f * dxv);
    float dif = -(c1 * dtv * (wm + wp - 2.0f * w0) / (dxv * dxv));
    float dis = -c2 * dtv * (w0 - wp) / dxv;
    float upd = adv + dif + dis;
    const float* urow = u + (size_t)(b * NXQ + t) * TQ;
    A[r * NXQ + t] = urow[TQ - 1] + w0;
    C[r * NXQ + t] = urow[TQ - 2] + w0 + upd;
  } else {
    int i = blk - N2;
    int j = t;
    float vi0 = vs[i * 3], vi1 = vs[i * 3 + 1], vi2 = vs[i * 3 + 2];
    float vj0 = vs[j * 3], vj1 = vs[j * 3 + 1], vj2 = vs[j * 3 + 2];
    float nvi = sqrtf(vi0 * vi0 + vi1 * vi1 + vi2 * vi2);
    float nvj = sqrtf(vj0 * vj0 + vj1 * vj1 + vj2 * vj2);
    float prod = sqrtf(fabsf(vi0 * vj0) + fabsf(vi1 * vj1) + fabsf(vi2 * vj2));
    float sim = prod / fmaxf(nvi, nvj);
    float ssv = 1.0f - 0.9f * sim;
    if (isnan(ssv)) ssv = 0.0f;
    SS[i * BQ + j] = ssv;
  }
}

// ---------------------------------------------------------------------------
// K2: SIM[i][j] = sum_x (A[j][x] - C[i][x])^2 ; 32x32 tile per block,
//     full K=256 staged in LDS (2 * 32 * 257 * 4B = 65.8 KB)
// ---------------------------------------------------------------------------
__global__ __launch_bounds__(256) void dist_kernel(const float* __restrict__ A,
                                                   const float* __restrict__ C,
                                                   float* __restrict__ SIM) {
  __shared__ float At[TILE * PITCH];
  __shared__ float Ct[TILE * PITCH];
  int t = threadIdx.x;
  int i0 = blockIdx.y * TILE;
  int j0 = blockIdx.x * TILE;
  for (int k = 0; k < TILE * NXQ / 256; k++) {
    int idx = k * 256 + t;
    int row = idx >> 8;
    int col = idx & (NXQ - 1);
    At[row * PITCH + col] = A[(j0 + row) * NXQ + col];
    Ct[row * PITCH + col] = C[(i0 + row) * NXQ + col];
  }
  __syncthreads();
  int ii = t >> 3;         // 0..31
  int jj = (t & 7) << 2;   // 0,4,...,28 -> 4 outputs each
  float acc0 = 0.f, acc1 = 0.f, acc2 = 0.f, acc3 = 0.f;
  for (int x = 0; x < NXQ; x++) {
    float cv = Ct[ii * PITCH + x];
    float d0 = At[(jj + 0) * PITCH + x] - cv;
    float d1 = At[(jj + 1) * PITCH + x] - cv;
    float d2 = At[(jj + 2) * PITCH + x] - cv;
    float d3 = At[(jj + 3) * PITCH + x] - cv;
    acc0 = fmaf(d0, d0, acc0);
    acc1 = fmaf(d1, d1, acc1);
    acc2 = fmaf(d2, d2, acc2);
    acc3 = fmaf(d3, d3, acc3);
  }
  float4 v = make_float4(acc0, acc1, acc2, acc3);
  *(float4*)&SIM[(i0 + ii) * N2 + j0 + jj] = v;
}

// ---------------------------------------------------------------------------
// K3: per-row logsumexp over [pos] + weighted negatives; ROW[r] = lse - pos
// ---------------------------------------------------------------------------
__global__ __launch_bounds__(256) void row_kernel(const float* __restrict__ SIM,
                                                  const float* __restrict__ SS,
                                                  double* __restrict__ ROW) {
  int r = blockIdx.x;
  int t = threadIdx.x;
  int rb = r & (BQ - 1);
  int jstar = (r + BQ) & (N2 - 1);  // positive column
  float posval = SIM[r * N2 + jstar];
  float ssv = SS[rb * BQ + t];  // weight for both j=t and j=t+256 (j%B == t)
  float v0, v1;
  {
    int j = t;
    if (j == jstar)                  v0 = posval;
    else if ((j & (BQ - 1)) == rb)   v0 = -INFINITY;  // excluded (j == r)
    else                             v0 = SIM[r * N2 + j] * ssv;
  }
  {
    int j = t + BQ;
    if (j == jstar)                  v1 = posval;
    else if ((j & (BQ - 1)) == rb)   v1 = -INFINITY;  // excluded
    else                             v1 = SIM[r * N2 + j] * ssv;
  }
  // block max
  float m = fmaxf(v0, v1);
  for (int off = 32; off > 0; off >>= 1) m = fmaxf(m, __shfl_down(m, off, 64));
  __shared__ float wmax[4];
  __shared__ double wsum[4];
  int wave = t >> 6, lane = t & 63;
  if (lane == 0) wmax[wave] = m;
  __syncthreads();
  float M = fmaxf(fmaxf(wmax[0], wmax[1]), fmaxf(wmax[2], wmax[3]));
  double s = 0.0;
  if (v0 != -INFINITY) s += exp((double)(v0 - M));
  if (v1 != -INFINITY) s += exp((double)(v1 - M));
  for (int off = 32; off > 0; off >>= 1) s += __shfl_down(s, off, 64);
  if (lane == 0) wsum[wave] = s;
  __syncthreads();
  if (t == 0) {
    double S = wsum[0] + wsum[1] + wsum[2] + wsum[3];
    ROW[r] = (double)M + log(S) - (double)posval;
  }
}

// ---------------------------------------------------------------------------
// K4: loss = sum(ROW) / (2B)
// ---------------------------------------------------------------------------
__global__ __launch_bounds__(256) void final_kernel(const double* __restrict__ ROW,
                                                    float* __restrict__ out) {
  int t = threadIdx.x;
  double s = ROW[t] + ROW[t + 256];
  for (int off = 32; off > 0; off >>= 1) s += __shfl_down(s, off, 64);
  __shared__ double wsum[4];
  int wave = t >> 6, lane = t & 63;
  if (lane == 0) wsum[wave] = s;
  __syncthreads();
  if (t == 0) {
    double S = wsum[0] + wsum[1] + wsum[2] + wsum[3];
    out[0] = (float)(S / (double)N2);
  }
}

extern "C" void kernel_launch(void* const* d_in, const int* in_sizes, int n_in,
                              void* d_out, int out_size, void* d_ws, size_t ws_size,
                              hipStream_t stream) {
  const float* x1 = (const float*)d_in[0];  // [B, NX, 1, 1]
  const float* x2 = (const float*)d_in[1];  // [B, NX, 1, 1]
  const float* u  = (const float*)d_in[2];  // [B, NX, T]
  const float* dt = (const float*)d_in[3];  // [B]
  const float* dx = (const float*)d_in[4];  // [1]
  const float* vs = (const float*)d_in[5];  // [B, 3]
  char* ws = (char*)d_ws;
  float*  SIM = (float*)(ws + 0);        // 512*512*4 = 1 MB
  float*  A   = (float*)(ws + 1048576);  // 512*256*4 = 512 KB
  float*  C   = (float*)(ws + 1572864);  // 512 KB
  float*  SS  = (float*)(ws + 2097152);  // 256*256*4 = 256 KB
  double* ROW = (double*)(ws + 2359296); // 512*8 = 4 KB
  float* out = (float*)d_out;

  prep_kernel<<<N2 + BQ, 256, 0, stream>>>(x1, x2, u, dt, dx, vs, A, C, SS);
  dim3 g2(N2 / TILE, N2 / TILE);
  dist_kernel<<<g2, 256, 0, stream>>>(A, C, SIM);
  row_kernel<<<N2, 256, 0, stream>>>(SIM, SS, ROW);
  final_kernel<<<1, 256, 0, stream>>>(ROW, out);
}